// Round 7
// baseline (1041.328 us; speedup 1.0000x reference)
//
#include <hip/hip_runtime.h>
#include <cstdint>

#define NPTS 8192
#define NB 8
#define DS 512
#define CF 64
#define KNN 32
#define NFPS 16
#define NWORK 112
#define NCOSI 64
#define NITEMS (NCOSI + 2 * NB * DS)  // 64 cos chunks + 8192 knn+group items

typedef float v2f __attribute__((ext_vector_type(2)));

// ---- DPP wave-64 reductions (VALU only) -----------------------------------
__device__ __forceinline__ float wave_max63(float x) {
  int v;
  v = __builtin_amdgcn_update_dpp(0, __float_as_int(x), 0x111, 0xf, 0xf, true); x = fmaxf(x, __int_as_float(v));
  v = __builtin_amdgcn_update_dpp(0, __float_as_int(x), 0x112, 0xf, 0xf, true); x = fmaxf(x, __int_as_float(v));
  v = __builtin_amdgcn_update_dpp(0, __float_as_int(x), 0x114, 0xf, 0xf, true); x = fmaxf(x, __int_as_float(v));
  v = __builtin_amdgcn_update_dpp(0, __float_as_int(x), 0x118, 0xf, 0xf, true); x = fmaxf(x, __int_as_float(v));
  v = __builtin_amdgcn_update_dpp(0, __float_as_int(x), 0x142, 0xf, 0xf, true); x = fmaxf(x, __int_as_float(v));
  v = __builtin_amdgcn_update_dpp(0, __float_as_int(x), 0x143, 0xf, 0xf, true); x = fmaxf(x, __int_as_float(v));
  return x;  // valid in lane 63
}

__device__ __forceinline__ float wave_sum_bcast(float x) {
  int v;
  v = __builtin_amdgcn_update_dpp(0, __float_as_int(x), 0x111, 0xf, 0xf, true); x += __int_as_float(v);
  v = __builtin_amdgcn_update_dpp(0, __float_as_int(x), 0x112, 0xf, 0xf, true); x += __int_as_float(v);
  v = __builtin_amdgcn_update_dpp(0, __float_as_int(x), 0x114, 0xf, 0xf, true); x += __int_as_float(v);
  v = __builtin_amdgcn_update_dpp(0, __float_as_int(x), 0x118, 0xf, 0xf, true); x += __int_as_float(v);
  v = __builtin_amdgcn_update_dpp(0, __float_as_int(x), 0x142, 0xf, 0xf, true); x += __int_as_float(v);
  v = __builtin_amdgcn_update_dpp(0, __float_as_int(x), 0x143, 0xf, 0xf, true); x += __int_as_float(v);
  return __int_as_float(__builtin_amdgcn_readlane(__float_as_int(x), 63));
}

// zero acc[0..8] + qhead([12]) + done([13]); idxbuf stays 0xAA-poisoned (the
// sentinel: any value >= 8192 means "not yet published").
__global__ __launch_bounds__(64) void zero_kernel(float* __restrict__ acc) {
  if (threadIdx.x < 16) acc[threadIdx.x] = 0.0f;
}

// scan lane-group-replicated 256-bin histograms, pick bin containing rrank
__device__ __forceinline__ void radix_scan8(int (*hist)[264], int rrank, int* s_bl, int t) {
  if (t < 64) {
    int h0 = 0, h1 = 0, h2 = 0, h3 = 0;
#pragma unroll
    for (int c = 0; c < 8; ++c) {
      h0 += hist[c][t * 4 + 0]; h1 += hist[c][t * 4 + 1];
      h2 += hist[c][t * 4 + 2]; h3 += hist[c][t * 4 + 3];
    }
    int s = h0 + h1 + h2 + h3;
    int inc = s;
#pragma unroll
    for (int o = 1; o < 64; o <<= 1) {
      int v = __shfl_up(inc, o, 64);
      if (t >= o) inc += v;
    }
    int exc = inc - s;
    bool has = (rrank >= exc) && (rrank < inc);
    unsigned long long mask = __ballot(has);
    int win = __ffsll(mask) - 1;
    int wexc = __shfl(exc, win, 64);
    int wh0 = __shfl(h0, win, 64), wh1 = __shfl(h1, win, 64);
    int wh2 = __shfl(h2, win, 64);
    int r2 = rrank - wexc;
    int bin, less;
    if (r2 < wh0) { bin = 0; less = 0; }
    else if (r2 < wh0 + wh1) { bin = 1; less = wh0; }
    else if (r2 < wh0 + wh1 + wh2) { bin = 2; less = wh0 + wh1; }
    else { bin = 3; less = wh0 + wh1 + wh2; }
    if (t == 0) { s_bl[0] = win * 4 + bin; s_bl[1] = wexc + less; }
  }
  __syncthreads();
}

// ONE fused kernel, 128 blocks x 512 thr, all co-resident (1 block/CU via LDS):
//   blocks 0..15  : FPS (exact R5 structure; idx published via release atomics)
//   blocks 16..127: persistent workers pulling items from an atomic queue:
//       items 0..63   = cos chunks (no deps, fill the early window)
//       items 64..8255 = knn+group for one query, m-major order so demand
//                        tracks the fps publish rate; spin-acquire on idxbuf[g]
//                        (0xAA poison >= 8192 = not-yet-published sentinel).
//   Last-done worker finalizes out[0]. Deadlock-free: 128 blocks always fit.
__global__ __launch_bounds__(512, 2) void fused_kernel(
    const float* __restrict__ logits, const float* __restrict__ logits1,
    const float* __restrict__ p0first, const float* __restrict__ p0sec,
    int* __restrict__ idxbuf, float* __restrict__ acc,
    int* __restrict__ qhead, int* __restrict__ done, float* __restrict__ out) {
  // fps branch LDS
  __shared__ float ldsP[NPTS * 3];          // 96 KB winner-lookup table
  __shared__ __align__(16) float wmax8[8];
  __shared__ unsigned long long winkey[2];
  // worker branch LDS
  __shared__ int hist[8][264];
  __shared__ int s_bl[2];
  __shared__ int ctr, eqctr;
  __shared__ int eq[256];
  __shared__ int nbr[KNN];
  __shared__ float Drows[33][CF];
  __shared__ float wloss[8];
  __shared__ int s_item, s_center;

  const int blk = blockIdx.x;
  const int t = threadIdx.x;

  if (blk < NFPS) {
    // ================= FPS (verbatim R5 structure, 462us/absmax 0) =========
    const int view = blk >> 3, b = blk & 7;
    const float* p = (view ? p0sec : p0first) + (size_t)b * NPTS * 3;
    int* idx_out = idxbuf + blk * DS;
    v2f px2[8], py2[8], pz2[8], dist2[8];
#pragma unroll
    for (int j = 0; j < 8; ++j) {
      int e0 = j * 512 + t, e1 = (j + 8) * 512 + t;
      px2[j] = (v2f){p[e0 * 3 + 0], p[e1 * 3 + 0]};
      py2[j] = (v2f){p[e0 * 3 + 1], p[e1 * 3 + 1]};
      pz2[j] = (v2f){p[e0 * 3 + 2], p[e1 * 3 + 2]};
      dist2[j] = (v2f){3.4e38f, 3.4e38f};
      ldsP[e0 * 3 + 0] = px2[j].x; ldsP[e1 * 3 + 0] = px2[j].y;
      ldsP[e0 * 3 + 1] = py2[j].x; ldsP[e1 * 3 + 1] = py2[j].y;
      ldsP[e0 * 3 + 2] = pz2[j].x; ldsP[e1 * 3 + 2] = pz2[j].y;
    }
#pragma unroll
    for (int j = 0; j < 8; ++j) {
      asm("" : "+v"(px2[j]), "+v"(py2[j]), "+v"(pz2[j]));  // no remat (R4)
    }
    if (t == 0) {
      __hip_atomic_store(&idx_out[0], 0, __ATOMIC_RELEASE, __HIP_MEMORY_SCOPE_AGENT);
      winkey[0] = 0ull; winkey[1] = 0ull;
    }
    float wx = p[0], wy = p[1], wz = p[2];  // seed = point 0
    const int lane = t & 63, wave = t >> 6;
    __syncthreads();
    for (int it = 0; it < DS - 1; ++it) {
      v2f wx2 = (v2f){wx, wx}, wy2 = (v2f){wy, wy}, wz2 = (v2f){wz, wz};
      v2f lm2 = (v2f){-1.0f, -1.0f};
#pragma unroll
      for (int j = 0; j < 8; ++j) {
        v2f dx = px2[j] - wx2, dy = py2[j] - wy2, dz = pz2[j] - wz2;
        v2f nd = dx * dx + dy * dy + dz * dz;
        v2f d = __builtin_elementwise_min(dist2[j], nd);
        dist2[j] = d;
        lm2 = __builtin_elementwise_max(lm2, d);
      }
      float lm = fmaxf(lm2.x, lm2.y);
      float wm = wave_max63(lm);
      if (lane == 63) wmax8[wave] = wm;
      if (t == 0) winkey[(it + 1) & 1] = 0ull;
      __syncthreads();  // bar1
      float4 m0 = *(const float4*)&wmax8[0];
      float4 m1 = *(const float4*)&wmax8[4];
      float gmax = fmaxf(fmaxf(fmaxf(m0.x, m0.y), fmaxf(m0.z, m0.w)),
                         fmaxf(fmaxf(m1.x, m1.y), fmaxf(m1.z, m1.w)));
      if (lm == gmax) {
        int jbest = 0;
#pragma unroll
        for (int jp = 15; jp >= 0; --jp) {
          int j = jp & 7, h = jp >> 3;
          float dv = h ? dist2[j].y : dist2[j].x;
          if (dv == lm) jbest = jp;
        }
        unsigned e = (unsigned)(jbest * 512 + t);
        unsigned long long key =
            (((unsigned long long)__float_as_uint(lm)) << 32) | (8191u - e);
        atomicMax(&winkey[it & 1], key);
      }
      __syncthreads();  // bar2
      unsigned long long k = winkey[it & 1];
      unsigned e = 8191u - (unsigned)(k & 0xffffffffu);
      if (t == 0)
        __hip_atomic_store(&idx_out[it + 1], (int)e, __ATOMIC_RELEASE,
                           __HIP_MEMORY_SCOPE_AGENT);
      wx = ldsP[e * 3 + 0]; wy = ldsP[e * 3 + 1]; wz = ldsP[e * 3 + 2];
    }
  } else {
    // ================= persistent worker ===================================
    const int lane = t & 63, wave = t >> 6;
    for (;;) {
      if (t == 0) s_item = atomicAdd(qhead, 1);
      __syncthreads();
      const int item = s_item;
      __syncthreads();
      if (item >= NITEMS) break;
      if (item < NCOSI) {
        // ---- cos chunk: rows item*1024 .. +1023, 2 rows/thread ----------
        float cv = 0.0f;
#pragma unroll
        for (int rr = 0; rr < 2; ++rr) {
          int row = item * 1024 + rr * 512 + t;
          const float4* A = (const float4*)(logits + (size_t)row * CF);
          const float4* Bv = (const float4*)(logits1 + (size_t)row * CF);
          float ab = 0.f, aa = 0.f, bb = 0.f;
#pragma unroll
          for (int i = 0; i < 16; ++i) {
            float4 a = A[i], c4 = Bv[i];
            ab += a.x * c4.x + a.y * c4.y + a.z * c4.z + a.w * c4.w;
            aa += a.x * a.x + a.y * a.y + a.z * a.z + a.w * a.w;
            bb += c4.x * c4.x + c4.y * c4.y + c4.z * c4.z + c4.w * c4.w;
          }
          cv += ab / fmaxf(sqrtf(aa) * sqrtf(bb), 1e-8f);
        }
        cv = wave_sum_bcast(cv);
        if (lane == 0) wloss[wave] = cv;
        __syncthreads();
        if (t == 0) {
          float s = 0.f;
#pragma unroll
          for (int w = 0; w < 8; ++w) s += wloss[w];
          atomicAdd(&acc[0], s);
        }
        __syncthreads();
      } else {
        // ---- knn+group for one query; m-major to track publish rate -----
        const int qi2 = item - NCOSI;
        const int m = qi2 >> 4, pair = qi2 & 15;
        const int g = pair * DS + m;
        const int view = pair >> 3, b = pair & 7;
        const float* p = (view ? p0sec : p0first) + (size_t)b * NPTS * 3;
        if (t == 0) {
          int ce;
          while ((unsigned)(ce = __hip_atomic_load(&idxbuf[g], __ATOMIC_ACQUIRE,
                                                   __HIP_MEMORY_SCOPE_AGENT)) >= 8192u)
            __builtin_amdgcn_s_sleep(2);
          s_center = ce;
        }
        __syncthreads();
        const int ci = s_center;
        const float qx = p[ci * 3], qy = p[ci * 3 + 1], qz = p[ci * 3 + 2];
        const float qq = qx * qx + qy * qy + qz * qz;
        const int c = t & 7;
        unsigned sk[16];
#pragma unroll
        for (int j = 0; j < 16; ++j) {
          int e = j * 512 + t;
          float sx = p[e * 3], sy = p[e * 3 + 1], sz = p[e * 3 + 2];
          float ss = sx * sx + sy * sy + sz * sz;
          float dt = qx * sx + qy * sy + qz * sz;
          float d = qq + ss - 2.0f * dt;  // same formula as reference
          unsigned u = __float_as_uint(d);
          u = (u & 0x80000000u) ? ~u : (u | 0x80000000u);  // sortable
          sk[j] = u;
        }
        int rrank = 31;
        unsigned prefix = 0;
        for (int k = t; k < 8 * 264; k += 512) ((int*)hist)[k] = 0;
        __syncthreads();
#pragma unroll
        for (int j = 0; j < 16; ++j) atomicAdd(&hist[c][sk[j] >> 24], 1);
        __syncthreads();
        radix_scan8(hist, rrank, s_bl, t);
        prefix = (unsigned)s_bl[0];
        rrank -= s_bl[1];
        for (int pass = 1; pass < 4; ++pass) {
          const int shift = 24 - pass * 8;
          for (int k = t; k < 8 * 264; k += 512) ((int*)hist)[k] = 0;
          __syncthreads();
#pragma unroll
          for (int j = 0; j < 16; ++j) {
            unsigned u = sk[j];
            if ((u >> (shift + 8)) == prefix) atomicAdd(&hist[c][(u >> shift) & 255], 1);
          }
          __syncthreads();
          radix_scan8(hist, rrank, s_bl, t);
          prefix = (prefix << 8) | (unsigned)s_bl[0];
          rrank -= s_bl[1];
        }
        if (t == 0) { ctr = 0; eqctr = 0; }
        __syncthreads();
        const unsigned V = prefix;
#pragma unroll
        for (int j = 0; j < 16; ++j) {
          unsigned u = sk[j];
          if (u < V) {
            int s = atomicAdd(&ctr, 1);
            nbr[s] = j * 512 + t;
          } else if (u == V) {
            int s2 = atomicAdd(&eqctr, 1);
            if (s2 < 256) eq[s2] = j * 512 + t;
          }
        }
        __syncthreads();
        if (t == 0) {
          int need = rrank + 1;
          int E = eqctr; if (E > 256) E = 256;
          int base = KNN - need;
          for (int s = 0; s < need; ++s) {
            int mi = 0;
            for (int i = 1; i < E; ++i)
              if (eq[i] < eq[mi]) mi = i;
            nbr[base + s] = eq[mi];
            eq[mi] = 0x7fffffff;
          }
        }
        __syncthreads();
        // ---- group loss (rows 0..31 = neighbors, row 32 = center) -------
        const float* f = (view ? logits1 : logits) + (size_t)b * NPTS * CF;
        for (int r = wave; r < 33; r += 8) {
          int e = (r < 32) ? nbr[r] : ci;
          Drows[r][lane] = f[(size_t)e * CF + lane];
        }
        __syncthreads();
        float avg = 0.0f;
#pragma unroll
        for (int r = 0; r < 33; ++r) avg += Drows[r][lane];
        avg *= (1.0f / 33.0f);
        float na = wave_sum_bcast(avg * avg);
        const float rsna = sqrtf(na);
        float loss = 0.0f;
        for (int r = wave; r < 33; r += 8) {
          float d = Drows[r][lane];
          float d0 = wave_sum_bcast(d * avg);
          float n0 = wave_sum_bcast(d * d);
          float den = fmaxf(sqrtf(n0) * rsna, 1e-8f);
          loss += -200.0f * (d0 / den) - 0.5f * log1pf(40.0f * n0);
        }
        if (lane == 0) wloss[wave] = loss;
        __syncthreads();
        if (t == 0) {
          float s = 0.f;
#pragma unroll
          for (int w = 0; w < 8; ++w) s += wloss[w];
          atomicAdd(&acc[1 + b], s * (1.0f / 33.0f));
        }
        __syncthreads();
      }
    }
    // ---- completion + last-block finalize --------------------------------
    __syncthreads();
    if (t == 0) {
      int d = __hip_atomic_fetch_add(done, 1, __ATOMIC_ACQ_REL, __HIP_MEMORY_SCOPE_AGENT);
      if (d == NWORK - 1) {
        float a0 = __hip_atomic_load(&acc[0], __ATOMIC_ACQUIRE, __HIP_MEMORY_SCOPE_AGENT);
        float gsum = 0.0f;
        for (int bb = 0; bb < 8; ++bb) {
          float Sb = __hip_atomic_load(&acc[1 + bb], __ATOMIC_ACQUIRE, __HIP_MEMORY_SCOPE_AGENT);
          gsum = (gsum + Sb) * (1.0f / 512.0f);  // *(1/512) == /512 exactly (pow2)
        }
        gsum *= 0.125f;  // / b
        out[0] = -a0 / 65536.0f + gsum + gsum;
      }
    }
  }
}

extern "C" void kernel_launch(void* const* d_in, const int* in_sizes, int n_in,
                              void* d_out, int out_size, void* d_ws, size_t ws_size,
                              hipStream_t stream) {
  (void)in_sizes; (void)n_in; (void)out_size; (void)ws_size;
  const float* logits  = (const float*)d_in[0];
  const float* logits1 = (const float*)d_in[1];
  const float* p0first = (const float*)d_in[2];
  const float* p0sec   = (const float*)d_in[3];
  float* out = (float*)d_out;

  float* acc = (float*)d_ws;           // [0]=cosSum, [1..8]=S[b], [12]=qhead, [13]=done
  int* qhead = (int*)d_ws + 12;
  int* done  = (int*)d_ws + 13;
  int* idxbuf = (int*)d_ws + 16;       // [2*8*512]; 0xAA poison = "unpublished" sentinel

  zero_kernel<<<1, 64, 0, stream>>>(acc);
  fused_kernel<<<NFPS + NWORK, 512, 0, stream>>>(logits, logits1, p0first, p0sec,
                                                 idxbuf, acc, qhead, done, out);
}

// Round 8
// 919.843 us; speedup vs baseline: 1.1321x; 1.1321x over previous
//
#include <hip/hip_runtime.h>
#include <cstdint>

#define NPTS 8192
#define NB 8
#define DS 512
#define CF 64
#define KNN 32
#define NFPS 16
#define NWORK 240
#define NCOSI 64
#define NITEMS (NCOSI + 2 * NB * DS)  // 64 cos chunks + 8192 knn+group items
#define DYNLDS 98304                  // max(fps ldsP 96KB, worker bufs ~42KB)

typedef float v2f __attribute__((ext_vector_type(2)));

// ---- DPP wave-64 reductions (VALU only) -----------------------------------
__device__ __forceinline__ float wave_max63(float x) {
  int v;
  v = __builtin_amdgcn_update_dpp(0, __float_as_int(x), 0x111, 0xf, 0xf, true); x = fmaxf(x, __int_as_float(v));
  v = __builtin_amdgcn_update_dpp(0, __float_as_int(x), 0x112, 0xf, 0xf, true); x = fmaxf(x, __int_as_float(v));
  v = __builtin_amdgcn_update_dpp(0, __float_as_int(x), 0x114, 0xf, 0xf, true); x = fmaxf(x, __int_as_float(v));
  v = __builtin_amdgcn_update_dpp(0, __float_as_int(x), 0x118, 0xf, 0xf, true); x = fmaxf(x, __int_as_float(v));
  v = __builtin_amdgcn_update_dpp(0, __float_as_int(x), 0x142, 0xf, 0xf, true); x = fmaxf(x, __int_as_float(v));
  v = __builtin_amdgcn_update_dpp(0, __float_as_int(x), 0x143, 0xf, 0xf, true); x = fmaxf(x, __int_as_float(v));
  return x;  // valid in lane 63
}

__device__ __forceinline__ float wave_sum_bcast(float x) {
  int v;
  v = __builtin_amdgcn_update_dpp(0, __float_as_int(x), 0x111, 0xf, 0xf, true); x += __int_as_float(v);
  v = __builtin_amdgcn_update_dpp(0, __float_as_int(x), 0x112, 0xf, 0xf, true); x += __int_as_float(v);
  v = __builtin_amdgcn_update_dpp(0, __float_as_int(x), 0x114, 0xf, 0xf, true); x += __int_as_float(v);
  v = __builtin_amdgcn_update_dpp(0, __float_as_int(x), 0x118, 0xf, 0xf, true); x += __int_as_float(v);
  v = __builtin_amdgcn_update_dpp(0, __float_as_int(x), 0x142, 0xf, 0xf, true); x += __int_as_float(v);
  v = __builtin_amdgcn_update_dpp(0, __float_as_int(x), 0x143, 0xf, 0xf, true); x += __int_as_float(v);
  return __int_as_float(__builtin_amdgcn_readlane(__float_as_int(x), 63));
}

// zero acc[0..8], qhead([12]), done([13]); idxbuf stays 0xAA-poisoned
// (any value >= 8192 == "not yet published" sentinel).
__global__ __launch_bounds__(64) void zero_kernel(float* __restrict__ acc) {
  if (threadIdx.x < 16) acc[threadIdx.x] = 0.0f;
}

// ONE fused kernel, 256 blocks x 512 thr. Dynamic LDS 98.3KB => 1 block/CU is
// the only placement the HW allows => all 256 blocks co-resident => the
// producer/consumer spin is deadlock-free by construction.
//   blocks 0..15  : FPS (R5 structure; idx published via agent release stores)
//   blocks 16..255: persistent workers; peek-before-claim queue (R7 lesson:
//                   claiming an unpublished item turns spin-wait into lost
//                   throughput); 3-pass 11/11/10-bit radix select.
__global__ __launch_bounds__(512, 2) void fused_kernel(
    const float* __restrict__ logits, const float* __restrict__ logits1,
    const float* __restrict__ p0first, const float* __restrict__ p0sec,
    int* __restrict__ idxbuf, float* __restrict__ acc,
    int* __restrict__ qhead, int* __restrict__ done, float* __restrict__ out) {
  extern __shared__ char smem[];
  // small statics (coexist with dynamic LDS)
  __shared__ __align__(16) float wmax8[8];
  __shared__ unsigned long long winkey[2];
  __shared__ int wtot[8];
  __shared__ int s_bl[2];
  __shared__ int ctr, eqctr, s_item, s_center;
  __shared__ float wloss[8];

  const int blk = blockIdx.x;
  const int t = threadIdx.x;

  if (blk < NFPS) {
    // ================= FPS (verbatim R5/R7 structure) ======================
    float* ldsP = (float*)smem;  // 96 KB winner-lookup table
    const int view = blk >> 3, b = blk & 7;
    const float* p = (view ? p0sec : p0first) + (size_t)b * NPTS * 3;
    int* idx_out = idxbuf + blk * DS;
    v2f px2[8], py2[8], pz2[8], dist2[8];
#pragma unroll
    for (int j = 0; j < 8; ++j) {
      int e0 = j * 512 + t, e1 = (j + 8) * 512 + t;
      px2[j] = (v2f){p[e0 * 3 + 0], p[e1 * 3 + 0]};
      py2[j] = (v2f){p[e0 * 3 + 1], p[e1 * 3 + 1]};
      pz2[j] = (v2f){p[e0 * 3 + 2], p[e1 * 3 + 2]};
      dist2[j] = (v2f){3.4e38f, 3.4e38f};
      ldsP[e0 * 3 + 0] = px2[j].x; ldsP[e1 * 3 + 0] = px2[j].y;
      ldsP[e0 * 3 + 1] = py2[j].x; ldsP[e1 * 3 + 1] = py2[j].y;
      ldsP[e0 * 3 + 2] = pz2[j].x; ldsP[e1 * 3 + 2] = pz2[j].y;
    }
#pragma unroll
    for (int j = 0; j < 8; ++j) {
      asm("" : "+v"(px2[j]), "+v"(py2[j]), "+v"(pz2[j]));  // no remat (R4)
    }
    if (t == 0) {
      __hip_atomic_store(&idx_out[0], 0, __ATOMIC_RELEASE, __HIP_MEMORY_SCOPE_AGENT);
      winkey[0] = 0ull; winkey[1] = 0ull;
    }
    float wx = p[0], wy = p[1], wz = p[2];  // seed = point 0
    const int lane = t & 63, wave = t >> 6;
    __syncthreads();
    for (int it = 0; it < DS - 1; ++it) {
      v2f wx2 = (v2f){wx, wx}, wy2 = (v2f){wy, wy}, wz2 = (v2f){wz, wz};
      v2f lm2 = (v2f){-1.0f, -1.0f};
#pragma unroll
      for (int j = 0; j < 8; ++j) {
        v2f dx = px2[j] - wx2, dy = py2[j] - wy2, dz = pz2[j] - wz2;
        v2f nd = dx * dx + dy * dy + dz * dz;
        v2f d = __builtin_elementwise_min(dist2[j], nd);
        dist2[j] = d;
        lm2 = __builtin_elementwise_max(lm2, d);
      }
      float lm = fmaxf(lm2.x, lm2.y);
      float wm = wave_max63(lm);
      if (lane == 63) wmax8[wave] = wm;
      if (t == 0) winkey[(it + 1) & 1] = 0ull;
      __syncthreads();  // bar1
      float4 m0 = *(const float4*)&wmax8[0];
      float4 m1 = *(const float4*)&wmax8[4];
      float gmax = fmaxf(fmaxf(fmaxf(m0.x, m0.y), fmaxf(m0.z, m0.w)),
                         fmaxf(fmaxf(m1.x, m1.y), fmaxf(m1.z, m1.w)));
      if (lm == gmax) {
        int jbest = 0;
#pragma unroll
        for (int jp = 15; jp >= 0; --jp) {
          int j = jp & 7, h = jp >> 3;
          float dv = h ? dist2[j].y : dist2[j].x;
          if (dv == lm) jbest = jp;
        }
        unsigned e = (unsigned)(jbest * 512 + t);
        unsigned long long key =
            (((unsigned long long)__float_as_uint(lm)) << 32) | (8191u - e);
        atomicMax(&winkey[it & 1], key);
      }
      __syncthreads();  // bar2
      unsigned long long k = winkey[it & 1];
      unsigned e = 8191u - (unsigned)(k & 0xffffffffu);
      if (t == 0)
        __hip_atomic_store(&idx_out[it + 1], (int)e, __ATOMIC_RELEASE,
                           __HIP_MEMORY_SCOPE_AGENT);
      wx = ldsP[e * 3 + 0]; wy = ldsP[e * 3 + 1]; wz = ldsP[e * 3 + 2];
    }
  } else {
    // ================= persistent worker ===================================
    int* hb0 = (int*)smem;                         // [2][2048] = 16 KB
    int* hb1 = (int*)(smem + 16384);               // [2][2048] = 16 KB
    float* Drows = (float*)(smem + 32768);         // [33][64] = 8448 B
    int* nbr = (int*)(smem + 41216);               // [32]
    int* eq = (int*)(smem + 41344);                // [256]
    const int lane = t & 63, wave = t >> 6;
    for (;;) {
      // ---- peek-before-claim: only claim items whose center is published --
      if (t == 0) {
        for (;;) {
          int it = __hip_atomic_load(qhead, __ATOMIC_RELAXED, __HIP_MEMORY_SCOPE_AGENT);
          if (it >= NITEMS || it < NCOSI) break;
          int q2 = it - NCOSI;
          int gg = (q2 & 15) * DS + (q2 >> 4);
          unsigned ce = (unsigned)__hip_atomic_load(&idxbuf[gg], __ATOMIC_RELAXED,
                                                    __HIP_MEMORY_SCOPE_AGENT);
          if (ce < 8192u) break;
          __builtin_amdgcn_s_sleep(8);
        }
        s_item = atomicAdd(qhead, 1);
      }
      __syncthreads();
      const int item = s_item;
      __syncthreads();
      if (item >= NITEMS) break;
      if (item < NCOSI) {
        // ---- cos chunk: rows item*1024 .. +1023, 2 rows/thread ------------
        float cv = 0.0f;
#pragma unroll
        for (int rr = 0; rr < 2; ++rr) {
          int row = item * 1024 + rr * 512 + t;
          const float4* A = (const float4*)(logits + (size_t)row * CF);
          const float4* Bv = (const float4*)(logits1 + (size_t)row * CF);
          float ab = 0.f, aa = 0.f, bb = 0.f;
#pragma unroll
          for (int i = 0; i < 16; ++i) {
            float4 a = A[i], c4 = Bv[i];
            ab += a.x * c4.x + a.y * c4.y + a.z * c4.z + a.w * c4.w;
            aa += a.x * a.x + a.y * a.y + a.z * a.z + a.w * a.w;
            bb += c4.x * c4.x + c4.y * c4.y + c4.z * c4.z + c4.w * c4.w;
          }
          cv += ab / fmaxf(sqrtf(aa) * sqrtf(bb), 1e-8f);
        }
        cv = wave_sum_bcast(cv);
        if (lane == 0) wloss[wave] = cv;
        __syncthreads();
        if (t == 0) {
          float s = 0.f;
#pragma unroll
          for (int w = 0; w < 8; ++w) s += wloss[w];
          atomicAdd(&acc[0], s);
        }
        __syncthreads();
      } else {
        // ---- knn+group for one query ---------------------------------------
        const int qi2 = item - NCOSI;
        const int m = qi2 >> 4, pair = qi2 & 15;
        const int g = pair * DS + m;
        const int view = pair >> 3, b = pair & 7;
        const float* p = (view ? p0sec : p0first) + (size_t)b * NPTS * 3;
        for (int k = t; k < 4096; k += 512) hb0[k] = 0;
        if (t == 0) {
          int ce;
          while ((unsigned)(ce = __hip_atomic_load(&idxbuf[g], __ATOMIC_ACQUIRE,
                                                   __HIP_MEMORY_SCOPE_AGENT)) >= 8192u)
            __builtin_amdgcn_s_sleep(2);
          s_center = ce;
        }
        __syncthreads();
        const int ci = s_center;
        const float qx = p[ci * 3], qy = p[ci * 3 + 1], qz = p[ci * 3 + 2];
        const float qq = qx * qx + qy * qy + qz * qz;
        const int cpy = (t & 1) << 11;  // histogram copy offset (2 copies)
        unsigned sk[16];
#pragma unroll
        for (int j = 0; j < 16; ++j) {
          int e = j * 512 + t;
          float sx = p[e * 3], sy = p[e * 3 + 1], sz = p[e * 3 + 2];
          float ss = sx * sx + sy * sy + sz * sz;
          float dt = qx * sx + qy * sy + qz * sz;
          float d = qq + ss - 2.0f * dt;  // same formula as reference
          unsigned u = __float_as_uint(d);
          u = (u & 0x80000000u) ? ~u : (u | 0x80000000u);  // sortable
          sk[j] = u;
        }
        int rrank = 31;
        // ---- pass A: top 11 bits, 2048 bins --------------------------------
#pragma unroll
        for (int j = 0; j < 16; ++j) atomicAdd(&hb0[cpy + (sk[j] >> 21)], 1);
        __syncthreads();
        unsigned pA, pAB, V;
        {
          int b0 = t << 2;
          int c0 = hb0[b0] + hb0[2048 + b0];
          int c1 = hb0[b0 + 1] + hb0[2048 + b0 + 1];
          int c2 = hb0[b0 + 2] + hb0[2048 + b0 + 2];
          int c3 = hb0[b0 + 3] + hb0[2048 + b0 + 3];
          int s = c0 + c1 + c2 + c3;
          int inc = s;
#pragma unroll
          for (int o = 1; o < 64; o <<= 1) {
            int v = __shfl_up(inc, o, 64);
            if (lane >= o) inc += v;
          }
          if (lane == 63) wtot[wave] = inc;
          for (int k = t; k < 4096; k += 512) hb1[k] = 0;  // zero B during scan
          __syncthreads();
          int off = 0;
#pragma unroll
          for (int w = 0; w < 8; ++w) off += (w < wave) ? wtot[w] : 0;
          int exc = off + inc - s;
          if (rrank >= exc && rrank < exc + s) {
            int r2 = rrank - exc; int bin, less;
            if (r2 < c0) { bin = 0; less = 0; }
            else if (r2 < c0 + c1) { bin = 1; less = c0; }
            else if (r2 < c0 + c1 + c2) { bin = 2; less = c0 + c1; }
            else { bin = 3; less = c0 + c1 + c2; }
            s_bl[0] = b0 + bin; s_bl[1] = exc + less;
          }
          __syncthreads();
          pA = (unsigned)s_bl[0];
          rrank -= s_bl[1];
        }
        // ---- pass B: bits [20:10], 2048 bins -------------------------------
#pragma unroll
        for (int j = 0; j < 16; ++j) {
          unsigned u = sk[j];
          if ((u >> 21) == pA) atomicAdd(&hb1[cpy + ((u >> 10) & 2047)], 1);
        }
        __syncthreads();
        {
          int b0 = t << 2;
          int c0 = hb1[b0] + hb1[2048 + b0];
          int c1 = hb1[b0 + 1] + hb1[2048 + b0 + 1];
          int c2 = hb1[b0 + 2] + hb1[2048 + b0 + 2];
          int c3 = hb1[b0 + 3] + hb1[2048 + b0 + 3];
          int s = c0 + c1 + c2 + c3;
          int inc = s;
#pragma unroll
          for (int o = 1; o < 64; o <<= 1) {
            int v = __shfl_up(inc, o, 64);
            if (lane >= o) inc += v;
          }
          if (lane == 63) wtot[wave] = inc;
          for (int k = t; k < 4096; k += 512) hb0[k] = 0;  // zero C buf
          __syncthreads();
          int off = 0;
#pragma unroll
          for (int w = 0; w < 8; ++w) off += (w < wave) ? wtot[w] : 0;
          int exc = off + inc - s;
          if (rrank >= exc && rrank < exc + s) {
            int r2 = rrank - exc; int bin, less;
            if (r2 < c0) { bin = 0; less = 0; }
            else if (r2 < c0 + c1) { bin = 1; less = c0; }
            else if (r2 < c0 + c1 + c2) { bin = 2; less = c0 + c1; }
            else { bin = 3; less = c0 + c1 + c2; }
            s_bl[0] = b0 + bin; s_bl[1] = exc + less;
          }
          __syncthreads();
          pAB = (pA << 11) | (unsigned)s_bl[0];
          rrank -= s_bl[1];
        }
        // ---- pass C: bits [9:0], 1024 bins ---------------------------------
        const int cpyC = (t & 1) << 10;
#pragma unroll
        for (int j = 0; j < 16; ++j) {
          unsigned u = sk[j];
          if ((u >> 10) == pAB) atomicAdd(&hb0[cpyC + (u & 1023)], 1);
        }
        __syncthreads();
        {
          int b0 = t << 1;
          int c0 = hb0[b0] + hb0[1024 + b0];
          int c1 = hb0[b0 + 1] + hb0[1024 + b0 + 1];
          int s = c0 + c1;
          int inc = s;
#pragma unroll
          for (int o = 1; o < 64; o <<= 1) {
            int v = __shfl_up(inc, o, 64);
            if (lane >= o) inc += v;
          }
          if (lane == 63) wtot[wave] = inc;
          __syncthreads();
          int off = 0;
#pragma unroll
          for (int w = 0; w < 8; ++w) off += (w < wave) ? wtot[w] : 0;
          int exc = off + inc - s;
          if (rrank >= exc && rrank < exc + s) {
            int r2 = rrank - exc;
            if (r2 < c0) { s_bl[0] = b0; s_bl[1] = exc; }
            else { s_bl[0] = b0 + 1; s_bl[1] = exc + c0; }
          }
          __syncthreads();
          V = (pAB << 10) | (unsigned)s_bl[0];
          rrank -= s_bl[1];
        }
        // ---- output set: keys < V, plus (rrank+1) smallest-index == V ------
        if (t == 0) { ctr = 0; eqctr = 0; }
        __syncthreads();
#pragma unroll
        for (int j = 0; j < 16; ++j) {
          unsigned u = sk[j];
          if (u < V) {
            int s = atomicAdd(&ctr, 1);
            nbr[s] = j * 512 + t;
          } else if (u == V) {
            int s2 = atomicAdd(&eqctr, 1);
            if (s2 < 256) eq[s2] = j * 512 + t;
          }
        }
        __syncthreads();
        if (t == 0) {
          int need = rrank + 1;
          int E = eqctr; if (E > 256) E = 256;
          int base = KNN - need;
          for (int s = 0; s < need; ++s) {
            int mi = 0;
            for (int i = 1; i < E; ++i)
              if (eq[i] < eq[mi]) mi = i;
            nbr[base + s] = eq[mi];
            eq[mi] = 0x7fffffff;
          }
        }
        __syncthreads();
        // ---- group loss (rows 0..31 = neighbors, row 32 = center) ----------
        const float* f = (view ? logits1 : logits) + (size_t)b * NPTS * CF;
        for (int r = wave; r < 33; r += 8) {
          int e = (r < 32) ? nbr[r] : ci;
          Drows[r * 64 + lane] = f[(size_t)e * CF + lane];
        }
        __syncthreads();
        float avg = 0.0f;
#pragma unroll
        for (int r = 0; r < 33; ++r) avg += Drows[r * 64 + lane];
        avg *= (1.0f / 33.0f);
        float na = wave_sum_bcast(avg * avg);
        const float rsna = sqrtf(na);
        float loss = 0.0f;
        for (int r = wave; r < 33; r += 8) {
          float d = Drows[r * 64 + lane];
          float d0 = wave_sum_bcast(d * avg);
          float n0 = wave_sum_bcast(d * d);
          float den = fmaxf(sqrtf(n0) * rsna, 1e-8f);
          loss += -200.0f * (d0 / den) - 0.5f * log1pf(40.0f * n0);
        }
        if (lane == 0) wloss[wave] = loss;
        __syncthreads();
        if (t == 0) {
          float s = 0.f;
#pragma unroll
          for (int w = 0; w < 8; ++w) s += wloss[w];
          atomicAdd(&acc[1 + b], s * (1.0f / 33.0f));
        }
        __syncthreads();
      }
    }
    // ---- completion + last-block finalize --------------------------------
    __syncthreads();
    if (t == 0) {
      int d = __hip_atomic_fetch_add(done, 1, __ATOMIC_ACQ_REL, __HIP_MEMORY_SCOPE_AGENT);
      if (d == NWORK - 1) {
        float a0 = __hip_atomic_load(&acc[0], __ATOMIC_ACQUIRE, __HIP_MEMORY_SCOPE_AGENT);
        float gsum = 0.0f;
        for (int bb = 0; bb < 8; ++bb) {
          float Sb = __hip_atomic_load(&acc[1 + bb], __ATOMIC_ACQUIRE, __HIP_MEMORY_SCOPE_AGENT);
          gsum = (gsum + Sb) * (1.0f / 512.0f);  // /512 exact (pow2)
        }
        gsum *= 0.125f;  // / b
        out[0] = -a0 / 65536.0f + gsum + gsum;
      }
    }
  }
}

extern "C" void kernel_launch(void* const* d_in, const int* in_sizes, int n_in,
                              void* d_out, int out_size, void* d_ws, size_t ws_size,
                              hipStream_t stream) {
  (void)in_sizes; (void)n_in; (void)out_size; (void)ws_size;
  const float* logits  = (const float*)d_in[0];
  const float* logits1 = (const float*)d_in[1];
  const float* p0first = (const float*)d_in[2];
  const float* p0sec   = (const float*)d_in[3];
  float* out = (float*)d_out;

  float* acc = (float*)d_ws;           // [0]=cosSum, [1..8]=S[b], [12]=qhead, [13]=done
  int* qhead = (int*)d_ws + 12;
  int* done  = (int*)d_ws + 13;
  int* idxbuf = (int*)d_ws + 16;       // [2*8*512]; 0xAA poison = "unpublished"

  zero_kernel<<<1, 64, 0, stream>>>(acc);
  fused_kernel<<<NFPS + NWORK, 512, DYNLDS, stream>>>(logits, logits1, p0first, p0sec,
                                                      idxbuf, acc, qhead, done, out);
}

// Round 9
// 683.228 us; speedup vs baseline: 1.5241x; 1.3463x over previous
//
#include <hip/hip_runtime.h>
#include <cstdint>

#define NPTS 8192
#define NB 8
#define DS 512
#define CF 64
#define KNN 32
#define NFPS 16
#define NWORK 240
#define NCOSI 64
#define NITEMS (NCOSI + 2 * NB * DS)  // 64 cos chunks + 8192 knn+group items
#define DYNLDS 98304                  // max(fps ldsP 96KB, worker bufs ~42KB)

typedef float v2f __attribute__((ext_vector_type(2)));

// ---- DPP wave-64 reductions (VALU only) -----------------------------------
__device__ __forceinline__ float wave_max63(float x) {
  int v;
  v = __builtin_amdgcn_update_dpp(0, __float_as_int(x), 0x111, 0xf, 0xf, true); x = fmaxf(x, __int_as_float(v));
  v = __builtin_amdgcn_update_dpp(0, __float_as_int(x), 0x112, 0xf, 0xf, true); x = fmaxf(x, __int_as_float(v));
  v = __builtin_amdgcn_update_dpp(0, __float_as_int(x), 0x114, 0xf, 0xf, true); x = fmaxf(x, __int_as_float(v));
  v = __builtin_amdgcn_update_dpp(0, __float_as_int(x), 0x118, 0xf, 0xf, true); x = fmaxf(x, __int_as_float(v));
  v = __builtin_amdgcn_update_dpp(0, __float_as_int(x), 0x142, 0xf, 0xf, true); x = fmaxf(x, __int_as_float(v));
  v = __builtin_amdgcn_update_dpp(0, __float_as_int(x), 0x143, 0xf, 0xf, true); x = fmaxf(x, __int_as_float(v));
  return x;  // valid in lane 63
}

__device__ __forceinline__ float wave_sum_bcast(float x) {
  int v;
  v = __builtin_amdgcn_update_dpp(0, __float_as_int(x), 0x111, 0xf, 0xf, true); x += __int_as_float(v);
  v = __builtin_amdgcn_update_dpp(0, __float_as_int(x), 0x112, 0xf, 0xf, true); x += __int_as_float(v);
  v = __builtin_amdgcn_update_dpp(0, __float_as_int(x), 0x114, 0xf, 0xf, true); x += __int_as_float(v);
  v = __builtin_amdgcn_update_dpp(0, __float_as_int(x), 0x118, 0xf, 0xf, true); x += __int_as_float(v);
  v = __builtin_amdgcn_update_dpp(0, __float_as_int(x), 0x142, 0xf, 0xf, true); x += __int_as_float(v);
  v = __builtin_amdgcn_update_dpp(0, __float_as_int(x), 0x143, 0xf, 0xf, true); x += __int_as_float(v);
  return __int_as_float(__builtin_amdgcn_readlane(__float_as_int(x), 63));
}

// zero acc[0..8] + done([13]); idxbuf stays 0xAA-poisoned (>=8192 sentinel).
__global__ __launch_bounds__(64) void zero_kernel(float* __restrict__ acc) {
  if (threadIdx.x < 16) acc[threadIdx.x] = 0.0f;
}

// ONE fused kernel, 256 blocks x 512 thr, dynamic LDS 98.3KB => 1 block/CU =>
// all 256 blocks co-resident => producer/consumer spin deadlock-free.
//   blocks 0..15  : FPS (R5 structure; idx published via agent release stores)
//   blocks 16..255: workers with STATIC staggered assignment (R8 lesson: a
//                   dynamic queue thundering-herds into committed waits):
//                   worker w takes items w, w+240, ... in m-major order, so
//                   each worker's waits pipeline against its own work.
__global__ __launch_bounds__(512, 2) void fused_kernel(
    const float* __restrict__ logits, const float* __restrict__ logits1,
    const float* __restrict__ p0first, const float* __restrict__ p0sec,
    int* __restrict__ idxbuf, float* __restrict__ acc,
    int* __restrict__ done, float* __restrict__ out) {
  extern __shared__ char smem[];
  __shared__ __align__(16) float wmax8[8];
  __shared__ unsigned long long winkey[2];
  __shared__ int wtot[8];
  __shared__ int s_bl[2];
  __shared__ int ctr, eqctr, s_center;
  __shared__ float wloss[8];

  const int blk = blockIdx.x;
  const int t = threadIdx.x;

  if (blk < NFPS) {
    // ================= FPS (verbatim R5/R8 structure) ======================
    float* ldsP = (float*)smem;  // 96 KB winner-lookup table
    const int view = blk >> 3, b = blk & 7;
    const float* p = (view ? p0sec : p0first) + (size_t)b * NPTS * 3;
    int* idx_out = idxbuf + blk * DS;
    v2f px2[8], py2[8], pz2[8], dist2[8];
#pragma unroll
    for (int j = 0; j < 8; ++j) {
      int e0 = j * 512 + t, e1 = (j + 8) * 512 + t;
      px2[j] = (v2f){p[e0 * 3 + 0], p[e1 * 3 + 0]};
      py2[j] = (v2f){p[e0 * 3 + 1], p[e1 * 3 + 1]};
      pz2[j] = (v2f){p[e0 * 3 + 2], p[e1 * 3 + 2]};
      dist2[j] = (v2f){3.4e38f, 3.4e38f};
      ldsP[e0 * 3 + 0] = px2[j].x; ldsP[e1 * 3 + 0] = px2[j].y;
      ldsP[e0 * 3 + 1] = py2[j].x; ldsP[e1 * 3 + 1] = py2[j].y;
      ldsP[e0 * 3 + 2] = pz2[j].x; ldsP[e1 * 3 + 2] = pz2[j].y;
    }
#pragma unroll
    for (int j = 0; j < 8; ++j) {
      asm("" : "+v"(px2[j]), "+v"(py2[j]), "+v"(pz2[j]));  // no remat (R4)
    }
    if (t == 0) {
      __hip_atomic_store(&idx_out[0], 0, __ATOMIC_RELEASE, __HIP_MEMORY_SCOPE_AGENT);
      winkey[0] = 0ull; winkey[1] = 0ull;
    }
    float wx = p[0], wy = p[1], wz = p[2];  // seed = point 0
    const int lane = t & 63, wave = t >> 6;
    __syncthreads();
    for (int it = 0; it < DS - 1; ++it) {
      v2f wx2 = (v2f){wx, wx}, wy2 = (v2f){wy, wy}, wz2 = (v2f){wz, wz};
      v2f lm2 = (v2f){-1.0f, -1.0f};
#pragma unroll
      for (int j = 0; j < 8; ++j) {
        v2f dx = px2[j] - wx2, dy = py2[j] - wy2, dz = pz2[j] - wz2;
        v2f nd = dx * dx + dy * dy + dz * dz;
        v2f d = __builtin_elementwise_min(dist2[j], nd);
        dist2[j] = d;
        lm2 = __builtin_elementwise_max(lm2, d);
      }
      float lm = fmaxf(lm2.x, lm2.y);
      float wm = wave_max63(lm);
      if (lane == 63) wmax8[wave] = wm;
      if (t == 0) winkey[(it + 1) & 1] = 0ull;
      __syncthreads();  // bar1
      float4 m0 = *(const float4*)&wmax8[0];
      float4 m1 = *(const float4*)&wmax8[4];
      float gmax = fmaxf(fmaxf(fmaxf(m0.x, m0.y), fmaxf(m0.z, m0.w)),
                         fmaxf(fmaxf(m1.x, m1.y), fmaxf(m1.z, m1.w)));
      if (lm == gmax) {
        int jbest = 0;
#pragma unroll
        for (int jp = 15; jp >= 0; --jp) {
          int j = jp & 7, h = jp >> 3;
          float dv = h ? dist2[j].y : dist2[j].x;
          if (dv == lm) jbest = jp;
        }
        unsigned e = (unsigned)(jbest * 512 + t);
        unsigned long long key =
            (((unsigned long long)__float_as_uint(lm)) << 32) | (8191u - e);
        atomicMax(&winkey[it & 1], key);
      }
      __syncthreads();  // bar2
      unsigned long long k = winkey[it & 1];
      unsigned e = 8191u - (unsigned)(k & 0xffffffffu);
      if (t == 0)
        __hip_atomic_store(&idx_out[it + 1], (int)e, __ATOMIC_RELEASE,
                           __HIP_MEMORY_SCOPE_AGENT);
      wx = ldsP[e * 3 + 0]; wy = ldsP[e * 3 + 1]; wz = ldsP[e * 3 + 2];
    }
  } else {
    // ================= worker: static staggered items ======================
    int* hb0 = (int*)smem;                         // [2][2048] = 16 KB
    int* hb1 = (int*)(smem + 16384);               // [2][2048] = 16 KB
    float* Drows = (float*)(smem + 32768);         // [33][64] = 8448 B
    int* nbr = (int*)(smem + 41216);               // [32]
    int* eq = (int*)(smem + 41344);                // [256]
    const int lane = t & 63, wave = t >> 6;
    const int w0 = blk - NFPS;  // 0..239
    for (int item = w0; item < NITEMS; item += NWORK) {
      if (item < NCOSI) {
        // ---- cos chunk: rows item*1024 .. +1023, 2 rows/thread ------------
        float cv = 0.0f;
#pragma unroll
        for (int rr = 0; rr < 2; ++rr) {
          int row = item * 1024 + rr * 512 + t;
          const float4* A = (const float4*)(logits + (size_t)row * CF);
          const float4* Bv = (const float4*)(logits1 + (size_t)row * CF);
          float ab = 0.f, aa = 0.f, bb = 0.f;
#pragma unroll
          for (int i = 0; i < 16; ++i) {
            float4 a = A[i], c4 = Bv[i];
            ab += a.x * c4.x + a.y * c4.y + a.z * c4.z + a.w * c4.w;
            aa += a.x * a.x + a.y * a.y + a.z * a.z + a.w * a.w;
            bb += c4.x * c4.x + c4.y * c4.y + c4.z * c4.z + c4.w * c4.w;
          }
          cv += ab / fmaxf(sqrtf(aa) * sqrtf(bb), 1e-8f);
        }
        cv = wave_sum_bcast(cv);
        if (lane == 0) wloss[wave] = cv;
        __syncthreads();
        if (t == 0) {
          float s = 0.f;
#pragma unroll
          for (int w = 0; w < 8; ++w) s += wloss[w];
          atomicAdd(&acc[0], s);
        }
        __syncthreads();
      } else {
        // ---- knn+group for one query --------------------------------------
        const int qi2 = item - NCOSI;
        const int m = qi2 >> 4, pair = qi2 & 15;
        const int g = pair * DS + m;
        const int view = pair >> 3, b = pair & 7;
        const float* p = (view ? p0sec : p0first) + (size_t)b * NPTS * 3;
        // vectorized point load: 16 consecutive points = 12 dwordx4 / thread
        float f48[48];
        {
          const float4* p4 = (const float4*)p;
#pragma unroll
          for (int i = 0; i < 12; ++i) {
            float4 v4 = p4[t * 12 + i];
            f48[i * 4 + 0] = v4.x; f48[i * 4 + 1] = v4.y;
            f48[i * 4 + 2] = v4.z; f48[i * 4 + 3] = v4.w;
          }
        }
        for (int k = t; k < 4096; k += 512) hb0[k] = 0;
        if (t == 0) {
          int ce;
          while ((unsigned)(ce = __hip_atomic_load(&idxbuf[g], __ATOMIC_ACQUIRE,
                                                   __HIP_MEMORY_SCOPE_AGENT)) >= 8192u)
            __builtin_amdgcn_s_sleep(2);
          s_center = ce;
        }
        __syncthreads();
        const int ci = s_center;
        const float qx = p[ci * 3], qy = p[ci * 3 + 1], qz = p[ci * 3 + 2];
        const float qq = qx * qx + qy * qy + qz * qz;
        const int cpy = (t & 1) << 11;  // histogram copy (2 copies)
        unsigned sk[16];  // keys for points e = t*16 + j
#pragma unroll
        for (int j = 0; j < 16; ++j) {
          float sx = f48[j * 3], sy = f48[j * 3 + 1], sz = f48[j * 3 + 2];
          float ss = sx * sx + sy * sy + sz * sz;
          float dt = qx * sx + qy * sy + qz * sz;
          float d = qq + ss - 2.0f * dt;  // same formula as reference
          unsigned u = __float_as_uint(d);
          u = (u & 0x80000000u) ? ~u : (u | 0x80000000u);  // sortable
          sk[j] = u;
        }
        int rrank = 31;
        // ---- pass A: top 11 bits, 2048 bins -------------------------------
#pragma unroll
        for (int j = 0; j < 16; ++j) atomicAdd(&hb0[cpy + (sk[j] >> 21)], 1);
        __syncthreads();
        unsigned pA, pAB, V;
        {
          int b0 = t << 2;
          int c0 = hb0[b0] + hb0[2048 + b0];
          int c1 = hb0[b0 + 1] + hb0[2048 + b0 + 1];
          int c2 = hb0[b0 + 2] + hb0[2048 + b0 + 2];
          int c3 = hb0[b0 + 3] + hb0[2048 + b0 + 3];
          int s = c0 + c1 + c2 + c3;
          int inc = s;
#pragma unroll
          for (int o = 1; o < 64; o <<= 1) {
            int v = __shfl_up(inc, o, 64);
            if (lane >= o) inc += v;
          }
          if (lane == 63) wtot[wave] = inc;
          for (int k = t; k < 4096; k += 512) hb1[k] = 0;  // zero B during scan
          __syncthreads();
          int off = 0;
#pragma unroll
          for (int w = 0; w < 8; ++w) off += (w < wave) ? wtot[w] : 0;
          int exc = off + inc - s;
          if (rrank >= exc && rrank < exc + s) {
            int r2 = rrank - exc; int bin, less;
            if (r2 < c0) { bin = 0; less = 0; }
            else if (r2 < c0 + c1) { bin = 1; less = c0; }
            else if (r2 < c0 + c1 + c2) { bin = 2; less = c0 + c1; }
            else { bin = 3; less = c0 + c1 + c2; }
            s_bl[0] = b0 + bin; s_bl[1] = exc + less;
          }
          __syncthreads();
          pA = (unsigned)s_bl[0];
          rrank -= s_bl[1];
        }
        // ---- pass B: bits [20:10], 2048 bins ------------------------------
#pragma unroll
        for (int j = 0; j < 16; ++j) {
          unsigned u = sk[j];
          if ((u >> 21) == pA) atomicAdd(&hb1[cpy + ((u >> 10) & 2047)], 1);
        }
        __syncthreads();
        {
          int b0 = t << 2;
          int c0 = hb1[b0] + hb1[2048 + b0];
          int c1 = hb1[b0 + 1] + hb1[2048 + b0 + 1];
          int c2 = hb1[b0 + 2] + hb1[2048 + b0 + 2];
          int c3 = hb1[b0 + 3] + hb1[2048 + b0 + 3];
          int s = c0 + c1 + c2 + c3;
          int inc = s;
#pragma unroll
          for (int o = 1; o < 64; o <<= 1) {
            int v = __shfl_up(inc, o, 64);
            if (lane >= o) inc += v;
          }
          if (lane == 63) wtot[wave] = inc;
          for (int k = t; k < 4096; k += 512) hb0[k] = 0;  // zero C buf
          __syncthreads();
          int off = 0;
#pragma unroll
          for (int w = 0; w < 8; ++w) off += (w < wave) ? wtot[w] : 0;
          int exc = off + inc - s;
          if (rrank >= exc && rrank < exc + s) {
            int r2 = rrank - exc; int bin, less;
            if (r2 < c0) { bin = 0; less = 0; }
            else if (r2 < c0 + c1) { bin = 1; less = c0; }
            else if (r2 < c0 + c1 + c2) { bin = 2; less = c0 + c1; }
            else { bin = 3; less = c0 + c1 + c2; }
            s_bl[0] = b0 + bin; s_bl[1] = exc + less;
          }
          __syncthreads();
          pAB = (pA << 11) | (unsigned)s_bl[0];
          rrank -= s_bl[1];
        }
        // ---- pass C: bits [9:0], 1024 bins --------------------------------
        const int cpyC = (t & 1) << 10;
#pragma unroll
        for (int j = 0; j < 16; ++j) {
          unsigned u = sk[j];
          if ((u >> 10) == pAB) atomicAdd(&hb0[cpyC + (u & 1023)], 1);
        }
        __syncthreads();
        {
          int b0 = t << 1;
          int c0 = hb0[b0] + hb0[1024 + b0];
          int c1 = hb0[b0 + 1] + hb0[1024 + b0 + 1];
          int s = c0 + c1;
          int inc = s;
#pragma unroll
          for (int o = 1; o < 64; o <<= 1) {
            int v = __shfl_up(inc, o, 64);
            if (lane >= o) inc += v;
          }
          if (lane == 63) wtot[wave] = inc;
          __syncthreads();
          int off = 0;
#pragma unroll
          for (int w = 0; w < 8; ++w) off += (w < wave) ? wtot[w] : 0;
          int exc = off + inc - s;
          if (rrank >= exc && rrank < exc + s) {
            int r2 = rrank - exc;
            if (r2 < c0) { s_bl[0] = b0; s_bl[1] = exc; }
            else { s_bl[0] = b0 + 1; s_bl[1] = exc + c0; }
          }
          __syncthreads();
          V = (pAB << 10) | (unsigned)s_bl[0];
          rrank -= s_bl[1];
        }
        // ---- output set: keys < V, plus (rrank+1) smallest-index == V -----
        if (t == 0) { ctr = 0; eqctr = 0; }
        __syncthreads();
#pragma unroll
        for (int j = 0; j < 16; ++j) {
          unsigned u = sk[j];
          if (u < V) {
            int s = atomicAdd(&ctr, 1);
            nbr[s] = t * 16 + j;
          } else if (u == V) {
            int s2 = atomicAdd(&eqctr, 1);
            if (s2 < 256) eq[s2] = t * 16 + j;
          }
        }
        __syncthreads();
        if (t == 0) {
          int need = rrank + 1;
          int E = eqctr; if (E > 256) E = 256;
          int base = KNN - need;
          for (int s = 0; s < need; ++s) {
            int mi = 0;
            for (int i = 1; i < E; ++i)
              if (eq[i] < eq[mi]) mi = i;
            nbr[base + s] = eq[mi];
            eq[mi] = 0x7fffffff;
          }
        }
        __syncthreads();
        // ---- group loss (rows 0..31 = neighbors, row 32 = center) ---------
        const float* f = (view ? logits1 : logits) + (size_t)b * NPTS * CF;
        for (int r = wave; r < 33; r += 8) {
          int e = (r < 32) ? nbr[r] : ci;
          Drows[r * 64 + lane] = f[(size_t)e * CF + lane];
        }
        __syncthreads();
        float avg = 0.0f;
#pragma unroll
        for (int r = 0; r < 33; ++r) avg += Drows[r * 64 + lane];
        avg *= (1.0f / 33.0f);
        float na = wave_sum_bcast(avg * avg);
        const float rsna = sqrtf(na);
        float loss = 0.0f;
        for (int r = wave; r < 33; r += 8) {
          float d = Drows[r * 64 + lane];
          float d0 = wave_sum_bcast(d * avg);
          float n0 = wave_sum_bcast(d * d);
          float den = fmaxf(sqrtf(n0) * rsna, 1e-8f);
          loss += -200.0f * (d0 / den) - 0.5f * log1pf(40.0f * n0);
        }
        if (lane == 0) wloss[wave] = loss;
        __syncthreads();
        if (t == 0) {
          float s = 0.f;
#pragma unroll
          for (int w = 0; w < 8; ++w) s += wloss[w];
          atomicAdd(&acc[1 + b], s * (1.0f / 33.0f));
        }
        __syncthreads();
      }
    }
    // ---- completion + last-block finalize --------------------------------
    __syncthreads();
    if (t == 0) {
      int d = __hip_atomic_fetch_add(done, 1, __ATOMIC_ACQ_REL, __HIP_MEMORY_SCOPE_AGENT);
      if (d == NWORK - 1) {
        float a0 = __hip_atomic_load(&acc[0], __ATOMIC_ACQUIRE, __HIP_MEMORY_SCOPE_AGENT);
        float gsum = 0.0f;
        for (int bb = 0; bb < 8; ++bb) {
          float Sb = __hip_atomic_load(&acc[1 + bb], __ATOMIC_ACQUIRE, __HIP_MEMORY_SCOPE_AGENT);
          gsum = (gsum + Sb) * (1.0f / 512.0f);  // /512 exact (pow2)
        }
        gsum *= 0.125f;  // / b
        out[0] = -a0 / 65536.0f + gsum + gsum;
      }
    }
  }
}

extern "C" void kernel_launch(void* const* d_in, const int* in_sizes, int n_in,
                              void* d_out, int out_size, void* d_ws, size_t ws_size,
                              hipStream_t stream) {
  (void)in_sizes; (void)n_in; (void)out_size; (void)ws_size;
  const float* logits  = (const float*)d_in[0];
  const float* logits1 = (const float*)d_in[1];
  const float* p0first = (const float*)d_in[2];
  const float* p0sec   = (const float*)d_in[3];
  float* out = (float*)d_out;

  float* acc = (float*)d_ws;           // [0]=cosSum, [1..8]=S[b], [13]=done
  int* done  = (int*)d_ws + 13;
  int* idxbuf = (int*)d_ws + 16;       // [2*8*512]; 0xAA poison = "unpublished"

  zero_kernel<<<1, 64, 0, stream>>>(acc);
  fused_kernel<<<NFPS + NWORK, 512, DYNLDS, stream>>>(logits, logits1, p0first, p0sec,
                                                      idxbuf, acc, done, out);
}